// Round 10
// baseline (77.150 us; speedup 1.0000x reference)
//
#include <hip/hip_runtime.h>
#include <math.h>

// Problem constants (match reference setup_inputs)
#define NN 4096
#define MM 128
#define QQ 64
#define DD 128
#define CC (MM * QQ)          // 8192 gemm "columns" (flattened m,q)

typedef float f32x4 __attribute__((ext_vector_type(4)));
typedef int   i32x4 __attribute__((ext_vector_type(4)));
typedef int   i32x8 __attribute__((ext_vector_type(8)));

#define AS1 __attribute__((address_space(1)))
#define AS3 __attribute__((address_space(3)))

// ---- prep: fp32 -> fp8 e4m3 (OCP) convert + exact fp32 squared norms ----
// (verbatim R9: plain stores; cross-kernel visibility from dispatch boundary)
__global__ __launch_bounds__(256)
void prep_kernel(const float* __restrict__ A, const float* __restrict__ B,
                 unsigned char* __restrict__ A8, unsigned char* __restrict__ B8,
                 float* __restrict__ a2, float* __restrict__ b2)
{
    const int row = blockIdx.x * 8 + (threadIdx.x >> 5);    // 0..12287
    const int l32 = threadIdx.x & 31;
    const float* src;
    unsigned char* dst;
    float* nrm;
    if (row < NN) { src = A + (size_t)row * DD; dst = A8 + (size_t)row * DD; nrm = a2 + row; }
    else {
        int r = row - NN;
        src = B + (size_t)r * DD; dst = B8 + (size_t)r * DD; nrm = b2 + r;
    }
    float4 v = ((const float4*)src)[l32];
    int pk = __builtin_amdgcn_cvt_pk_fp8_f32(v.x, v.y, 0, false);   // bytes 0,1
    pk     = __builtin_amdgcn_cvt_pk_fp8_f32(v.z, v.w, pk, true);   // bytes 2,3
    ((int*)dst)[l32] = pk;
    float s = v.x * v.x + v.y * v.y + v.z * v.z + v.w * v.w;
    #pragma unroll
    for (int m = 16; m > 0; m >>= 1) s += __shfl_xor(s, m, 64);  // stays in 32-group
    if (l32 == 0) *nrm = s;
}

// ---- dens: 256n x 128c per block (2 A-tiles + 1 B-tile staged in ONE burst),
// then straight-line compute with ZERO further __syncthreads.
// Theory (R10): the per-tile sync forced vmcnt(0) on the next tile's
// global_load_lds every iteration -- 4 whole-block waits/block on ~500-900cy
// MALL latency was the ~3x stall over the exp/MFMA floor. One burst + one
// sync amortizes the wait; read-only LDS after that means waves drift freely.
__global__ __launch_bounds__(256)
void kde_dens_kernel(const unsigned char* __restrict__ A8,   // [NN][DD] fp8
                     const unsigned char* __restrict__ B8,   // [CC][DD] fp8
                     const float* __restrict__ var,
                     const float* __restrict__ a2w,          // [NN]
                     const float* __restrict__ b2w,          // [CC]
                     float* __restrict__ dpc)                // [MM][NN] transposed
{
    __shared__ unsigned char As[2 * 128 * DD];   // 32 KB (two adjacent n-tiles)
    __shared__ unsigned char Bs[128 * DD];       // 16 KB
    __shared__ float a2s[256];
    __shared__ float b2s[128];

    // XCD swizzle: same-cb blocks share an XCD -> B-tile L2/MALL reuse
    const int lin = blockIdx.x;                 // 0..1023
    const int xcd = lin & 7;
    const int loc = lin >> 3;                   // 0..127
    const int cb  = (xcd << 3) | (loc & 7);     // 0..63
    const int nb2 = loc >> 3;                   // 0..15
    const int n0  = nb2 * 256;
    const int c0  = cb * 128;

    const int t = threadIdx.x, w = t >> 6, lane = t & 63;

    // ---- single staging burst: 2048 A-chunks + 1024 B-chunks (16 B each) ----
    {
        const unsigned char* Ab = A8 + (size_t)n0 * DD;
        const unsigned char* Bb = B8 + (size_t)c0 * DD;
        #pragma unroll
        for (int i = 0; i < 8; ++i) {
            const int slot = w * 512 + i * 64 + lane;       // 0..2047
            const int r = slot >> 3;                        // row 0..255 (tile*128+r)
            const int c16 = slot & 7, scb = c16 ^ (r & 7);  // XOR chunk swizzle
            __builtin_amdgcn_global_load_lds(
                (const AS1 unsigned int*)(Ab + (size_t)r * DD + scb * 16),
                (AS3 unsigned int*)&As[slot * 16], 16, 0, 0);
        }
        #pragma unroll
        for (int i = 0; i < 4; ++i) {
            const int slot = w * 256 + i * 64 + lane;       // 0..1023
            const int r = slot >> 3, c16 = slot & 7, scb = c16 ^ (r & 7);
            __builtin_amdgcn_global_load_lds(
                (const AS1 unsigned int*)(Bb + (size_t)r * DD + scb * 16),
                (AS3 unsigned int*)&Bs[slot * 16], 16, 0, 0);
        }
        a2s[t] = a2w[n0 + t];                               // 256 values
        if (t < 128) b2s[t] = b2w[c0 + t];
    }
    __syncthreads();   // the ONLY barrier: drains vmcnt(0) incl. global_load_lds

    // ---- wave (wy,wx): rows wy*64+[0,64) of each tile, cols wx*64+[0,64) ----
    const int l15 = lane & 15, q = lane >> 4, xr = l15 & 7;
    const int wy = w >> 1, wx = w & 1;
    const int rbase = wy * 64, cbase = wx * 64;
    const int m = (cb << 1) + wx;
    const float hinvL = (0.5f / var[0]) * 1.44269504088896f;  // 0.5/var * log2(e)
    const float h2L   = hinvL + hinvL;

    // c-side factors + B-fragments: read ONCE, shared by both n-tiles
    f32x4 nbh[4];
    i32x8 b8v[4];
    #pragma unroll
    for (int jc = 0; jc < 4; ++jc) {
        const f32x4 bv = *(const f32x4*)&b2s[cbase + jc * 16 + q * 4];
        nbh[jc] = -bv * hinvL;
        const int ro = (cbase + jc * 16 + l15) * DD;
        const i32x4 lo = *(const i32x4*)&Bs[ro + (((q << 1) | 0) ^ xr) * 16];
        const i32x4 hi = *(const i32x4*)&Bs[ro + (((q << 1) | 1) ^ xr) * 16];
        #pragma unroll
        for (int e = 0; e < 4; ++e) { b8v[jc][e] = lo[e]; b8v[jc][4 + e] = hi[e]; }
    }

    #pragma unroll
    for (int t4 = 0; t4 < 2; ++t4) {
        // A fragments: lane holds A[t4*128 + rbase+i*16+l15][q*32 .. q*32+31]
        i32x8 a8[4];
        #pragma unroll
        for (int i = 0; i < 4; ++i) {
            const int ro = ((t4 << 7) + rbase + i * 16 + l15) * DD;
            const i32x4 lo = *(const i32x4*)&As[ro + (((q << 1) | 0) ^ xr) * 16];
            const i32x4 hi = *(const i32x4*)&As[ro + (((q << 1) | 1) ^ xr) * 16];
            #pragma unroll
            for (int e = 0; e < 4; ++e) { a8[i][e] = lo[e]; a8[i][4 + e] = hi[e]; }
        }

        // Swapped operands -> c-reduction in-register. 16 independent MFMAs.
        f32x4 acc[4][4] = {};
        #pragma unroll
        for (int jc = 0; jc < 4; ++jc)
            #pragma unroll
            for (int i = 0; i < 4; ++i)
                acc[jc][i] = __builtin_amdgcn_mfma_scale_f32_16x16x128_f8f6f4(
                                b8v[jc], a8[i], acc[jc][i],
                                0, 0,          // cbsz=0 (fp8), blgp=0 (fp8)
                                0, 127,        // scale_a = 1.0
                                0, 127);       // scale_b = 1.0

        // epilogue: dens = exp2(log2e*(2ab - a2 - b2)*0.5/var);
        // 16 c lane-local -> 2 partial chains + 4-way over q (2 shfl_xor).
        float sums[4];
        #pragma unroll
        for (int i = 0; i < 4; ++i) {
            const float aih = a2s[(t4 << 7) + rbase + i * 16 + l15] * hinvL;
            float s0 = 0.f, s1 = 0.f;
            #pragma unroll
            for (int jc = 0; jc < 4; jc += 2) {
                #pragma unroll
                for (int r = 0; r < 4; ++r) {
                    s0 += __builtin_amdgcn_exp2f(fmaf(h2L, acc[jc][i][r],     nbh[jc][r]     - aih));
                    s1 += __builtin_amdgcn_exp2f(fmaf(h2L, acc[jc + 1][i][r], nbh[jc + 1][r] - aih));
                }
            }
            float s = s0 + s1;
            s += __shfl_xor(s, 16, 64);
            s += __shfl_xor(s, 32, 64);
            sums[i] = s;   // full 64-col sum for n = t4*128 + rbase + i*16 + l15
        }
        // lane owns n = t4*128 + rbase + lane (i == q); static select; coalesced
        const float v01 = (q & 1) ? sums[1] : sums[0];
        const float v23 = (q & 1) ? sums[3] : sums[2];
        const float myv = (q & 2) ? v23 : v01;
        dpc[(size_t)m * NN + n0 + (t4 << 7) + rbase + lane] = myv;
    }
}

// ---- normalize: out[n,m] = dpc[m,n] / (sum_m dpc[:,n] + 1e-10) ----
// (verbatim R9: 256 blocks x 16 n; m-ascending sum order)
__global__ __launch_bounds__(256)
void kde_norm_kernel(const float* __restrict__ dpc, float* __restrict__ out)
{
    __shared__ float tile[128][17];    // [m][nloc], odd stride
    __shared__ float rden[16];
    const int n0 = blockIdx.x * 16;
    const int t  = threadIdx.x;

    const int mr = t >> 1, half = t & 1;   // 128 rows x 2 threads
    {
        const float4 va = *(const float4*)&dpc[(size_t)mr * NN + n0 + half * 8];
        const float4 vb = *(const float4*)&dpc[(size_t)mr * NN + n0 + half * 8 + 4];
        float* tr = &tile[mr][half * 8];
        tr[0] = va.x; tr[1] = va.y; tr[2] = va.z; tr[3] = va.w;
        tr[4] = vb.x; tr[5] = vb.y; tr[6] = vb.z; tr[7] = vb.w;
    }
    __syncthreads();

    if (t < 16) {
        float s = 0.f;
        #pragma unroll 8
        for (int mm = 0; mm < MM; ++mm) s += tile[mm][t];   // m ascending, matches ref
        rden[t] = 1.f / (s + 1e-10f);
    }
    __syncthreads();

    const int j = t >> 4, m0 = (t & 15) * 8;
    const float r = rden[j];
    float4 o0, o1;
    o0.x = tile[m0][j] * r;     o0.y = tile[m0 + 1][j] * r;
    o0.z = tile[m0 + 2][j] * r; o0.w = tile[m0 + 3][j] * r;
    o1.x = tile[m0 + 4][j] * r; o1.y = tile[m0 + 5][j] * r;
    o1.z = tile[m0 + 6][j] * r; o1.w = tile[m0 + 7][j] * r;
    float* obase = &out[(size_t)(n0 + j) * MM + m0];
    *(float4*)obase       = o0;
    *(float4*)(obase + 4) = o1;   // 512B per 16-thread group, coalesced
}

extern "C" void kernel_launch(void* const* d_in, const int* in_sizes, int n_in,
                              void* d_out, int out_size, void* d_ws, size_t ws_size,
                              hipStream_t stream) {
    const float* A   = (const float*)d_in[0];   // [4096][128]
    const float* B   = (const float*)d_in[1];   // [128][64][128] = [8192][128]
    const float* var = (const float*)d_in[2];   // [1]
    float* out = (float*)d_out;                 // [4096][128]

    unsigned char* A8 = (unsigned char*)d_ws;            // 512 KB
    unsigned char* B8 = A8 + (size_t)NN * DD;            // 1 MB
    float* a2  = (float*)(B8 + (size_t)CC * DD);         // 16 KB
    float* b2  = a2 + NN;                                // 32 KB
    float* dpc = b2 + CC;                                // 2 MB, [MM][NN]

    prep_kernel<<<(NN + CC) / 8, 256, 0, stream>>>(A, B, A8, B8, a2, b2);
    kde_dens_kernel<<<1024, 256, 0, stream>>>(A8, B8, var, a2, b2, dpc);
    kde_norm_kernel<<<NN / 16, 256, 0, stream>>>(dpc, out);
}